// Round 2
// baseline (22174.002 us; speedup 1.0000x reference)
//
#include <hip/hip_runtime.h>

// Problem constants (B=8, C=32, H=192, W=320)
#define IMH 192
#define IMW 320
#define HW_ (IMH * IMW)      // 61440
#define BB 8
#define FC 32                // feature channels

// ---------------------------------------------------------------------------
// 1. bilinear 2x upsample (half-pixel centers, edge clamp) * 2.0  [full batch]
// ---------------------------------------------------------------------------
__global__ __launch_bounds__(256) void upsample_k(const float* __restrict__ in,
                                                  float* __restrict__ out) {
    int gid = blockIdx.x * 256 + threadIdx.x;
    const int total = BB * 4 * IMH * IMW;
    if (gid >= total) return;
    int ox = gid % IMW;
    int t  = gid / IMW;
    int oy = t % IMH;
    int bc = t / IMH;  // b*4 + ch
    const int Hin = IMH / 2, Win = IMW / 2;
    float sy = oy * 0.5f - 0.25f;
    float sx = ox * 0.5f - 0.25f;
    float fy = floorf(sy), fx = floorf(sx);
    float ty_ = sy - fy, tx_ = sx - fx;
    int y0 = (int)fy, x0 = (int)fx;
    int y1 = y0 + 1, x1 = x0 + 1;
    y0 = max(0, min(Hin - 1, y0)); y1 = max(0, min(Hin - 1, y1));
    x0 = max(0, min(Win - 1, x0)); x1 = max(0, min(Win - 1, x1));
    const float* p = in + (long)bc * Hin * Win;
    float v00 = p[y0 * Win + x0], v01 = p[y0 * Win + x1];
    float v10 = p[y1 * Win + x0], v11 = p[y1 * Win + x1];
    float v = (1.f - ty_) * ((1.f - tx_) * v00 + tx_ * v01) +
              ty_ * ((1.f - tx_) * v10 + tx_ * v11);
    out[gid] = 2.f * v;
}

// ---------------------------------------------------------------------------
// 2. zero-init
// ---------------------------------------------------------------------------
__global__ __launch_bounds__(256) void zero_k(float* __restrict__ p, int n) {
    int gid = blockIdx.x * 256 + threadIdx.x;
    int stride = gridDim.x * 256;
    for (int i = gid; i < n; i += stride) p[i] = 0.f;
}

// ---------------------------------------------------------------------------
// 3. softsplat scatter-add over nb local batches.
//    feat/biflow pointers are PRE-OFFSET to the group's batch base.
// ---------------------------------------------------------------------------
__global__ __launch_bounds__(256) void splat_k(const float* __restrict__ feat,
                                               const float* __restrict__ biflow,
                                               int fbase,
                                               float* __restrict__ acc, int nb) {
    int gid = blockIdx.x * 256 + threadIdx.x;
    if (gid >= nb * HW_) return;
    int b = gid / HW_;          // local batch
    int p = gid - b * HW_;
    int y = p / IMW, x = p - y * IMW;
    const float* fl = biflow + ((long)b * 4 + fbase) * HW_;
    float fx = x + fl[p];
    float fy = y + fl[HW_ + p];
    float x0f = floorf(fx), y0f = floorf(fy);
    float wx1 = fx - x0f, wy1 = fy - y0f;
    float wx0 = 1.f - wx1, wy0 = 1.f - wy1;
    int ix0 = (int)x0f, iy0 = (int)y0f;

    float f[FC];
#pragma unroll
    for (int c = 0; c < FC; ++c) f[c] = feat[((long)b * FC + c) * HW_ + p];

    float* accb = acc + (long)b * 33 * HW_;
    const int ixs[4] = {ix0, ix0 + 1, ix0, ix0 + 1};
    const int iys[4] = {iy0, iy0, iy0 + 1, iy0 + 1};
    const float ww[4] = {wx0 * wy0, wx1 * wy0, wx0 * wy1, wx1 * wy1};
#pragma unroll
    for (int k = 0; k < 4; ++k) {
        int ix = ixs[k], iy = iys[k];
        float w = ww[k];
        if (ix < 0 || ix >= IMW || iy < 0 || iy >= IMH || w == 0.f) continue;
        int q = iy * IMW + ix;
#pragma unroll
        for (int c = 0; c < FC; ++c) atomicAdd(&accb[c * HW_ + q], f[c] * w);
        atomicAdd(&accb[32 * HW_ + q], w);
    }
}

// ---------------------------------------------------------------------------
// 4. normalize: warped[c] = acc[c] / (norm==0 ? 1 : norm)
// ---------------------------------------------------------------------------
__global__ __launch_bounds__(256) void norm_k(float* __restrict__ acc, int nb) {
    int gid = blockIdx.x * 256 + threadIdx.x;
    if (gid >= nb * HW_) return;
    int b = gid / HW_;
    int p = gid - b * HW_;
    float* accb = acc + (long)b * 33 * HW_;
    float n = accb[32 * HW_ + p];
    float inv = (n == 0.f) ? 1.f : (1.f / n);
#pragma unroll
    for (int c = 0; c < FC; ++c) accb[c * HW_ + p] *= inv;
}

// ---------------------------------------------------------------------------
// 5. correlation volume (9x9, mean over 32 ch) + leaky
// ---------------------------------------------------------------------------
__global__ __launch_bounds__(256) void corr_k(const float* __restrict__ w0,
                                              const float* __restrict__ w1,
                                              float* __restrict__ vol, int nb) {
    int gid = blockIdx.x * 256 + threadIdx.x;
    if (gid >= nb * HW_) return;
    int b = gid / HW_;
    int p = gid - b * HW_;
    int y = p / IMW, x = p - y * IMW;
    const float* a0 = w0 + (long)b * 33 * HW_;
    const float* a1 = w1 + (long)b * 33 * HW_;
    float f[FC];
#pragma unroll
    for (int c = 0; c < FC; ++c) f[c] = a0[c * HW_ + p];
    float* vb = vol + (long)b * 81 * HW_ + p;
    for (int dy = 0; dy < 9; ++dy) {
        int yy = y + dy - 4;
        for (int dx = 0; dx < 9; ++dx) {
            int xx = x + dx - 4;
            float s = 0.f;
            if ((unsigned)yy < IMH && (unsigned)xx < IMW) {
                int q = yy * IMW + xx;
#pragma unroll
                for (int c = 0; c < FC; ++c) s = fmaf(f[c], a1[c * HW_ + q], s);
                s *= (1.f / 32.f);
            }
            s = (s >= 0.f) ? s : 0.1f * s;
            vb[(dy * 9 + dx) * HW_] = s;
        }
    }
}

// ---------------------------------------------------------------------------
// 6. direct conv3x3, SAME, no bias. Tile 64x4 pixels, Cin chunked by 4 into
//    LDS, each thread holds all COUT accumulators. Up to 3 input segments
//    (virtual concat). blockIdx.y = LOCAL batch; global tensors pre-offset.
// ---------------------------------------------------------------------------
template <int COUT, bool LK, bool FIN>
__global__ __launch_bounds__(256) void conv_k(
    const float* __restrict__ s0, int a0, int u0,
    const float* __restrict__ s1, int a1, int u1,
    const float* __restrict__ s2, int a2, int u2,
    const float* __restrict__ Wt, int CinTot,
    float* __restrict__ outp, const float* __restrict__ bfp, int chBase) {
    const int tid = threadIdx.x;
    const int tx = tid & 63;
    const int ty = tid >> 6;
    const int bxi = blockIdx.x % 5;   // IMW/64 = 5
    const int byi = blockIdx.x / 5;   // IMH/4 = 48
    const int b = blockIdx.y;         // local batch
    const int bx0 = bxi * 64, by0 = byi * 4;
    const int x = bx0 + tx, y = by0 + ty;

    __shared__ float sIn[4][6][66];

    float acc[COUT];
#pragma unroll
    for (int i = 0; i < COUT; ++i) acc[i] = 0.f;

    const float* srcs[3] = {s0, s1, s2};
    const int alloc[3] = {a0, a1, a2};
    const int use[3] = {u0, u1, u2};
    int cinBase = 0;
#pragma unroll
    for (int seg = 0; seg < 3; ++seg) {
        const int cin = use[seg];
        if (cin == 0) break;
        const float* src = srcs[seg] + (long)b * alloc[seg] * HW_;
        for (int cc = 0; cc < cin; cc += 4) {
            __syncthreads();
            for (int idx = tid; idx < 4 * 6 * 66; idx += 256) {
                int c = idx / (6 * 66);
                int rem = idx - c * (6 * 66);
                int r = rem / 66;
                int col = rem - r * 66;
                int gy = by0 + r - 1;
                int gx = bx0 + col - 1;
                int cs = cc + c;
                float v = 0.f;
                if (cs < cin && (unsigned)gy < IMH && (unsigned)gx < IMW)
                    v = src[cs * HW_ + gy * IMW + gx];
                sIn[c][r][col] = v;
            }
            __syncthreads();
#pragma unroll
            for (int c = 0; c < 4; ++c) {
                if (cc + c >= cin) break;
                float v00 = sIn[c][ty + 0][tx + 0], v01 = sIn[c][ty + 0][tx + 1], v02 = sIn[c][ty + 0][tx + 2];
                float v10 = sIn[c][ty + 1][tx + 0], v11 = sIn[c][ty + 1][tx + 1], v12 = sIn[c][ty + 1][tx + 2];
                float v20 = sIn[c][ty + 2][tx + 0], v21 = sIn[c][ty + 2][tx + 1], v22 = sIn[c][ty + 2][tx + 2];
                const float* wr = Wt + (cinBase + cc + c) * 9;
#pragma unroll
                for (int oc = 0; oc < COUT; ++oc) {
                    const float* wp = wr + oc * CinTot * 9;
                    acc[oc] = fmaf(v00, wp[0], acc[oc]);
                    acc[oc] = fmaf(v01, wp[1], acc[oc]);
                    acc[oc] = fmaf(v02, wp[2], acc[oc]);
                    acc[oc] = fmaf(v10, wp[3], acc[oc]);
                    acc[oc] = fmaf(v11, wp[4], acc[oc]);
                    acc[oc] = fmaf(v12, wp[5], acc[oc]);
                    acc[oc] = fmaf(v20, wp[6], acc[oc]);
                    acc[oc] = fmaf(v21, wp[7], acc[oc]);
                    acc[oc] = fmaf(v22, wp[8], acc[oc]);
                }
            }
        }
        cinBase += cin;
    }

#pragma unroll
    for (int oc = 0; oc < COUT; ++oc) {
        float v = acc[oc];
        if (LK) v = (v >= 0.f) ? v : 0.1f * v;
        if (FIN) {
            int oidx = ((b * 4 + chBase + oc) * IMH + y) * IMW + x;
            outp[oidx] = bfp[oidx] + v;
        } else {
            outp[((b * COUT + oc) * IMH + y) * IMW + x] = v;
        }
    }
}

// ---------------------------------------------------------------------------
// launch — ws-size-adaptive batch grouping
// ---------------------------------------------------------------------------
extern "C" void kernel_launch(void* const* d_in, const int* in_sizes, int n_in,
                              void* d_out, int out_size, void* d_ws, size_t ws_size,
                              hipStream_t stream) {
    const float* f0  = (const float*)d_in[0];
    const float* f1  = (const float*)d_in[1];
    const float* bfp = (const float*)d_in[2];
    const float* ftf = (const float*)d_in[3];
    const float* btf = (const float*)d_in[4];
    const float* W1  = (const float*)d_in[5];
    const float* W2  = (const float*)d_in[6];
    const float* W3  = (const float*)d_in[7];
    const float* W4  = (const float*)d_in[8];
    const float* W5  = (const float*)d_in[9];
    const float* W6  = (const float*)d_in[10];
    const float* W7  = (const float*)d_in[11];
    float* out = (float*)d_out;
    float* ws  = (float*)d_ws;

    // Adaptive layout: full biflow (B*4*HW floats) + NB-batch group buffers.
    // Per-batch group cost: (33+33+81+64+64)*HW = 275*HW floats.
    const size_t wsf  = ws_size / sizeof(float);
    const size_t BIFL = (size_t)BB * 4 * HW_;          // 1,966,080
    const size_t PERB = (size_t)275 * HW_;             // 16,896,000
    int NB = 1;
    if (wsf > BIFL) {
        size_t t = (wsf - BIFL) / PERB;
        NB = (t >= (size_t)BB) ? BB : (t < 1 ? 1 : (int)t);
    }

    float* biflow = ws;                                 // [B,4,H,W]
    float* warp0  = biflow + BIFL;                      // [NB,33,H,W]
    float* warp1  = warp0 + (size_t)NB * 33 * HW_;      // [NB,33,H,W]
    float* volume = warp1 + (size_t)NB * 33 * HW_;      // [NB,81,H,W]
    float* buf1   = volume + (size_t)NB * 81 * HW_;     // [NB,64,H,W]
    float* buf2   = buf1 + (size_t)NB * 64 * HW_;       // [NB,64,H,W]

    upsample_k<<<(BB * 4 * HW_ + 255) / 256, 256, 0, stream>>>(bfp, biflow);

    for (int g = 0; g < BB; g += NB) {
        const int nb = (BB - g < NB) ? (BB - g) : NB;
        const int npix = nb * HW_;
        const float* f0g  = f0 + (size_t)g * FC * HW_;
        const float* f1g  = f1 + (size_t)g * FC * HW_;
        const float* ftfg = ftf + (size_t)g * FC * HW_;
        const float* btfg = btf + (size_t)g * FC * HW_;
        const float* bflg = biflow + (size_t)g * 4 * HW_;
        float* outg = out + (size_t)g * 4 * HW_;

        zero_k<<<2048, 256, 0, stream>>>(warp0, nb * 33 * HW_);
        zero_k<<<2048, 256, 0, stream>>>(warp1, nb * 33 * HW_);
        splat_k<<<(npix + 255) / 256, 256, 0, stream>>>(f0g, bflg, 0, warp0, nb);
        splat_k<<<(npix + 255) / 256, 256, 0, stream>>>(f1g, bflg, 2, warp1, nb);
        norm_k<<<(npix + 255) / 256, 256, 0, stream>>>(warp0, nb);
        norm_k<<<(npix + 255) / 256, 256, 0, stream>>>(warp1, nb);
        corr_k<<<(npix + 255) / 256, 256, 0, stream>>>(warp0, warp1, volume, nb);

        dim3 cg(240, nb);
        for (int pass = 0; pass < 2; ++pass) {
            const float* wp = pass ? warp1 : warp0;
            const float* tf = pass ? btfg : ftfg;
            int chB = pass ? 2 : 0;
            conv_k<64, false, false><<<cg, 256, 0, stream>>>(wp, 33, 32, tf, 32, 32, volume, 81, 81, W1, 145, buf1, nullptr, 0);
            conv_k<64, false, false><<<cg, 256, 0, stream>>>(buf1, 64, 64, nullptr, 0, 0, nullptr, 0, 0, W2, 64, buf2, nullptr, 0);
            conv_k<64, true,  false><<<cg, 256, 0, stream>>>(buf2, 64, 64, nullptr, 0, 0, nullptr, 0, 0, W3, 64, buf1, nullptr, 0);
            conv_k<32, false, false><<<cg, 256, 0, stream>>>(buf1, 64, 64, nullptr, 0, 0, nullptr, 0, 0, W4, 64, buf2, nullptr, 0);
            conv_k<32, false, false><<<cg, 256, 0, stream>>>(buf2, 32, 32, nullptr, 0, 0, nullptr, 0, 0, W5, 32, buf1, nullptr, 0);
            conv_k<16, false, false><<<cg, 256, 0, stream>>>(buf1, 32, 32, nullptr, 0, 0, nullptr, 0, 0, W6, 32, buf2, nullptr, 0);
            conv_k<2,  true,  true ><<<cg, 256, 0, stream>>>(buf2, 16, 16, nullptr, 0, 0, nullptr, 0, 0, W7, 16, outg, bflg, chB);
        }
    }
}

// Round 4
// 6403.333 us; speedup vs baseline: 3.4629x; 3.4629x over previous
//
#include <hip/hip_runtime.h>

// Problem constants (B=8, C=32, H=192, W=320)
#define IMH 192
#define IMW 320
#define HW_ (IMH * IMW)      // 61440
#define BB 8
#define FC 32

typedef unsigned short ushortT;
typedef __attribute__((ext_vector_type(8))) short short8;   // 8 bf16 = 4 VGPRs
typedef __attribute__((ext_vector_type(4))) float f32x4;

union FragU { uint4 u; short8 s8; };

__device__ __forceinline__ ushortT f2bf(float x) {
    union { float f; unsigned u; } v; v.f = x;
    unsigned r = v.u + 0x7FFF + ((v.u >> 16) & 1);   // RNE
    return (ushortT)(r >> 16);
}
__device__ __forceinline__ float lk(float v) { return (v >= 0.f) ? v : 0.1f * v; }

// ---------------------------------------------------------------------------
// 1. bilinear 2x upsample (half-pixel centers, edge clamp) * 2.0  [full batch]
// ---------------------------------------------------------------------------
__global__ __launch_bounds__(256) void upsample_k(const float* __restrict__ in,
                                                  float* __restrict__ out) {
    int gid = blockIdx.x * 256 + threadIdx.x;
    const int total = BB * 4 * IMH * IMW;
    if (gid >= total) return;
    int ox = gid % IMW;
    int t  = gid / IMW;
    int oy = t % IMH;
    int bc = t / IMH;
    const int Hin = IMH / 2, Win = IMW / 2;
    float sy = oy * 0.5f - 0.25f;
    float sx = ox * 0.5f - 0.25f;
    float fy = floorf(sy), fx = floorf(sx);
    float ty_ = sy - fy, tx_ = sx - fx;
    int y0 = (int)fy, x0 = (int)fx;
    int y1 = y0 + 1, x1 = x0 + 1;
    y0 = max(0, min(Hin - 1, y0)); y1 = max(0, min(Hin - 1, y1));
    x0 = max(0, min(Win - 1, x0)); x1 = max(0, min(Win - 1, x1));
    const float* p = in + (long)bc * Hin * Win;
    float v00 = p[y0 * Win + x0], v01 = p[y0 * Win + x1];
    float v10 = p[y1 * Win + x0], v11 = p[y1 * Win + x1];
    float v = (1.f - ty_) * ((1.f - tx_) * v00 + tx_ * v01) +
              ty_ * ((1.f - tx_) * v10 + tx_ * v11);
    out[gid] = 2.f * v;
}

// ---------------------------------------------------------------------------
// 2. zero-init (16B granules)
// ---------------------------------------------------------------------------
__global__ __launch_bounds__(256) void zero4_k(uint4* __restrict__ p, long n) {
    long gid = (long)blockIdx.x * 256 + threadIdx.x;
    long stride = (long)gridDim.x * 256;
    uint4 z = make_uint4(0, 0, 0, 0);
    for (long i = gid; i < n; i += stride) p[i] = z;
}

// ---------------------------------------------------------------------------
// 3. softsplat scatter-add (fp32 NCHW accumulators), nb local batches,
//    feat/biflow pre-offset to group base
// ---------------------------------------------------------------------------
__global__ __launch_bounds__(256) void splat_k(const float* __restrict__ feat,
                                               const float* __restrict__ biflow,
                                               int fbase,
                                               float* __restrict__ acc, int nb) {
    int gid = blockIdx.x * 256 + threadIdx.x;
    if (gid >= nb * HW_) return;
    int b = gid / HW_;
    int p = gid - b * HW_;
    int y = p / IMW, x = p - y * IMW;
    const float* fl = biflow + ((long)b * 4 + fbase) * HW_;
    float fx = x + fl[p];
    float fy = y + fl[HW_ + p];
    float x0f = floorf(fx), y0f = floorf(fy);
    float wx1 = fx - x0f, wy1 = fy - y0f;
    float wx0 = 1.f - wx1, wy0 = 1.f - wy1;
    int ix0 = (int)x0f, iy0 = (int)y0f;

    float f[FC];
#pragma unroll
    for (int c = 0; c < FC; ++c) f[c] = feat[((long)b * FC + c) * HW_ + p];

    float* accb = acc + (long)b * 33 * HW_;
    const int ixs[4] = {ix0, ix0 + 1, ix0, ix0 + 1};
    const int iys[4] = {iy0, iy0, iy0 + 1, iy0 + 1};
    const float ww[4] = {wx0 * wy0, wx1 * wy0, wx0 * wy1, wx1 * wy1};
#pragma unroll
    for (int k = 0; k < 4; ++k) {
        int ix = ixs[k], iy = iys[k];
        float w = ww[k];
        if (ix < 0 || ix >= IMW || iy < 0 || iy >= IMH || w == 0.f) continue;
        int q = iy * IMW + ix;
#pragma unroll
        for (int c = 0; c < FC; ++c) atomicAdd(&accb[c * HW_ + q], f[c] * w);
        atomicAdd(&accb[32 * HW_ + q], w);
    }
}

// ---------------------------------------------------------------------------
// 4. normalize in place (fp32)
// ---------------------------------------------------------------------------
__global__ __launch_bounds__(256) void norm_k(float* __restrict__ acc, int nb) {
    int gid = blockIdx.x * 256 + threadIdx.x;
    if (gid >= nb * HW_) return;
    int b = gid / HW_;
    int p = gid - b * HW_;
    float* accb = acc + (long)b * 33 * HW_;
    float n = accb[32 * HW_ + p];
    float inv = (n == 0.f) ? 1.f : (1.f / n);
#pragma unroll
    for (int c = 0; c < FC; ++c) accb[c * HW_ + p] *= inv;
}

// ---------------------------------------------------------------------------
// 5. correlation volume (9x9, mean over 32 ch) + leaky -> concat ch64..144 bf16
// ---------------------------------------------------------------------------
__global__ __launch_bounds__(256) void corr_k(const float* __restrict__ w0,
                                              const float* __restrict__ w1,
                                              ushortT* __restrict__ concat, int nb) {
    int gid = blockIdx.x * 256 + threadIdx.x;
    if (gid >= nb * HW_) return;
    int b = gid / HW_;
    int p = gid - b * HW_;
    int y = p / IMW, x = p - y * IMW;
    const float* a0 = w0 + (long)b * 33 * HW_;
    const float* a1 = w1 + (long)b * 33 * HW_;
    float f[FC];
#pragma unroll
    for (int c = 0; c < FC; ++c) f[c] = a0[c * HW_ + p];
    ushortT* vb = concat + ((long)b * HW_ + p) * 160 + 64;
    for (int dy = 0; dy < 9; ++dy) {
        int yy = y + dy - 4;
        for (int dx = 0; dx < 9; ++dx) {
            int xx = x + dx - 4;
            float s = 0.f;
            if ((unsigned)yy < IMH && (unsigned)xx < IMW) {
                int q = yy * IMW + xx;
#pragma unroll
                for (int c = 0; c < FC; ++c) s = fmaf(f[c], a1[c * HW_ + q], s);
                s *= (1.f / 32.f);
            }
            vb[dy * 9 + dx] = f2bf(lk(s));
        }
    }
}

// ---------------------------------------------------------------------------
// 6. fill concat ch0..63: warped (fp32 NCHW, normalized) + temporal (pre-offset)
// ---------------------------------------------------------------------------
__global__ __launch_bounds__(256) void fill_k(const float* __restrict__ warp,
                                              const float* __restrict__ tf,
                                              ushortT* __restrict__ concat, int nb) {
    int gid = blockIdx.x * 256 + threadIdx.x;
    if (gid >= nb * HW_ * 8) return;
    int c8 = gid & 7;
    int t = gid >> 3;
    int p = t % HW_;
    int b = t / HW_;
    int ch = c8 * 8;
    const float* src = (ch < 32) ? warp + ((long)b * 33 + ch) * HW_ + p
                                 : tf + ((long)b * 32 + (ch - 32)) * HW_ + p;
    ushortT pk[8];
#pragma unroll
    for (int j = 0; j < 8; ++j) pk[j] = f2bf(src[(long)j * HW_]);
    *(uint4*)&concat[((long)b * HW_ + p) * 160 + ch] = *(uint4*)pk;
}

// ---------------------------------------------------------------------------
// 7. weight transform: W[oc][cin][3][3] fp32 -> Wb[tap][ocp][cinp] bf16 (pad 0)
// ---------------------------------------------------------------------------
__global__ __launch_bounds__(256) void wconv_k(const float* __restrict__ W,
                                               ushortT* __restrict__ dst,
                                               int OC, int OCp, int CIN, int CINp) {
    int gid = blockIdx.x * 256 + threadIdx.x;
    int total = 9 * OCp * CINp;
    if (gid >= total) return;
    int cin = gid % CINp;
    int t = gid / CINp;
    int oc = t % OCp;
    int tap = t / OCp;
    float v = 0.f;
    if (oc < OC && cin < CIN) v = W[((long)oc * CIN + cin) * 9 + tap];
    dst[gid] = f2bf(v);
}

// ---------------------------------------------------------------------------
// 8. MFMA implicit-GEMM conv3x3 (SAME). Block = 256 thr = 4 waves; tile = one
//    row x 64 px. Wave w owns 16-px N-tile, loops MT M-tiles (16 oc).
//    K = cin chunked by 32; 9 taps = 9 accumulated GEMMs.
//    A frag: oc=lane&15, k=quad*8+j (Wb[tap][oc][cin], contiguous cin).
//    B frag: px=lane&15, k=quad*8+j (NHWC LDS tile, stride 36).
//    D:      px=lane&15, oc=quad*4+reg.
// ---------------------------------------------------------------------------
template <int MT, int KC, bool LK, bool FIN>
__global__ __launch_bounds__(256) void mconv_k(
    const ushortT* __restrict__ act, int actStride, int cinReal,
    const ushortT* __restrict__ Wb,
    ushortT* __restrict__ outp, int outStride,
    const float* __restrict__ bfp, float* __restrict__ fout, int chBase) {

    const int CINp = KC * 32;
    const int OCp = MT * 16;
    const int tid = threadIdx.x;
    const int lane = tid & 63;
    const int wv = tid >> 6;
    const int l15 = lane & 15;
    const int quad = lane >> 4;
    const int x0 = blockIdx.x * 64;    // 5 tiles
    const int y = blockIdx.y;          // 192
    const int b = blockIdx.z;          // local batch

    __shared__ ushortT sAct[3 * 66 * 36];   // 14.26 KB

    f32x4 acc[MT];
#pragma unroll
    for (int i = 0; i < MT; ++i) acc[i] = (f32x4)0.f;

    const long pixBase = (long)b * HW_;

    for (int kc = 0; kc < KC; ++kc) {
        __syncthreads();
        // stage 3 rows x 66 px x 32 ch (4 units of 8ch per site)
        for (int u = tid; u < 3 * 66 * 4; u += 256) {
            int c8 = u & 3;
            int site = u >> 2;
            int ky = site / 66;
            int xi = site - ky * 66;
            int gy = y + ky - 1;
            int gx = x0 + xi - 1;
            int cBeg = kc * 32 + c8 * 8;
            ushortT* dp = &sAct[site * 36 + c8 * 8];
            if ((unsigned)gy < IMH && (unsigned)gx < IMW && cBeg < cinReal) {
                const ushortT* sp = act + ((pixBase + (long)gy * IMW + gx) * actStride + cBeg);
                if (cBeg + 8 <= cinReal) {
                    const uint2* sq = (const uint2*)sp;
                    ((uint2*)dp)[0] = sq[0];
                    ((uint2*)dp)[1] = sq[1];
                } else {
#pragma unroll
                    for (int j = 0; j < 8; ++j)
                        dp[j] = (cBeg + j < cinReal) ? sp[j] : (ushortT)0;
                }
            } else {
                uint2 z = make_uint2(0, 0);
                ((uint2*)dp)[0] = z;
                ((uint2*)dp)[1] = z;
            }
        }
        __syncthreads();

#pragma unroll
        for (int tap = 0; tap < 9; ++tap) {
            const int ky = tap / 3, kx = tap % 3;
            const int xi = wv * 16 + l15 + kx;
            const uint2* bp = (const uint2*)&sAct[(ky * 66 + xi) * 36 + quad * 8];
            FragU bf;
            uint2 b0 = bp[0], b1 = bp[1];
            bf.u = make_uint4(b0.x, b0.y, b1.x, b1.y);
            const ushortT* wp = Wb + (((long)tap * OCp + l15) * CINp + kc * 32 + quad * 8);
#pragma unroll
            for (int mt = 0; mt < MT; ++mt) {
                FragU af;
                af.u = *(const uint4*)(wp + (long)mt * 16 * CINp);
                acc[mt] = __builtin_amdgcn_mfma_f32_16x16x32_bf16(af.s8, bf.s8, acc[mt], 0, 0, 0);
            }
        }
    }

    const int px = x0 + wv * 16 + l15;
    if (FIN) {
        if (quad == 0) {
#pragma unroll
            for (int r = 0; r < 2; ++r) {
                float v = lk(acc[0][r]);
                long o = ((long)(b * 4 + chBase + r) * IMH + y) * IMW + px;
                fout[o] = bfp[o] + v;
            }
        }
    } else {
        long obase = (pixBase + (long)y * IMW + px) * outStride;
#pragma unroll
        for (int mt = 0; mt < MT; ++mt) {
            int oc = mt * 16 + quad * 4;
            ushortT pk[4];
#pragma unroll
            for (int r = 0; r < 4; ++r) {
                float v = acc[mt][r];
                if (LK) v = lk(v);
                pk[r] = f2bf(v);
            }
            *(uint2*)&outp[obase + oc] = *(uint2*)pk;
        }
    }
}

// ---------------------------------------------------------------------------
// launch — ws-size-adaptive batch grouping (round-2 evidence: ws in [75,143) MB)
// ---------------------------------------------------------------------------
extern "C" void kernel_launch(void* const* d_in, const int* in_sizes, int n_in,
                              void* d_out, int out_size, void* d_ws, size_t ws_size,
                              hipStream_t stream) {
    const float* f0  = (const float*)d_in[0];
    const float* f1  = (const float*)d_in[1];
    const float* bfp = (const float*)d_in[2];
    const float* ftf = (const float*)d_in[3];
    const float* btf = (const float*)d_in[4];
    const float* W1  = (const float*)d_in[5];
    const float* W2  = (const float*)d_in[6];
    const float* W3  = (const float*)d_in[7];
    const float* W4  = (const float*)d_in[8];
    const float* W5  = (const float*)d_in[9];
    const float* W6  = (const float*)d_in[10];
    const float* W7  = (const float*)d_in[11];
    float* out = (float*)d_out;

    // ---- adaptive layout ----
    // fixed: biflow (B*4*HW fp32) + transposed weights (202,752 bf16)
    // per-batch: acc0+acc1 (66*HW fp32) + concat (160*HW bf16) + bufA/B (128*HW bf16)
    //          = 840 B/px = 51,609,600 B
    char* base = (char*)d_ws;
    size_t off = 0;
    auto alloc = [&](size_t bytes) { char* p = base + off; off += (bytes + 255) & ~(size_t)255; return p; };

    float* biflow = (float*)alloc((size_t)BB * 4 * HW_ * 4);
    ushortT* WbL1 = (ushortT*)alloc((size_t)9 * 64 * 160 * 2);
    ushortT* WbL2 = (ushortT*)alloc((size_t)9 * 64 * 64 * 2);
    ushortT* WbL3 = (ushortT*)alloc((size_t)9 * 64 * 64 * 2);
    ushortT* WbL4 = (ushortT*)alloc((size_t)9 * 32 * 64 * 2);
    ushortT* WbL5 = (ushortT*)alloc((size_t)9 * 32 * 32 * 2);
    ushortT* WbL6 = (ushortT*)alloc((size_t)9 * 16 * 32 * 2);
    ushortT* WbL7 = (ushortT*)alloc((size_t)9 * 16 * 32 * 2);

    const size_t PERB = (size_t)840 * HW_;   // bytes per batch (with per-buffer padding slack below)
    size_t remain = (ws_size > off + 4096) ? (ws_size - off - 4096) : 0;
    int NB = (int)(remain / (PERB + 2048));
    if (NB < 1) NB = 1;
    if (NB > BB) NB = BB;

    float*   acc0   = (float*)alloc((size_t)NB * 33 * HW_ * 4);
    float*   acc1   = (float*)alloc((size_t)NB * 33 * HW_ * 4);
    ushortT* concat = (ushortT*)alloc((size_t)NB * HW_ * 160 * 2);
    ushortT* bufA   = (ushortT*)alloc((size_t)NB * HW_ * 64 * 2);
    ushortT* bufB   = (ushortT*)alloc((size_t)NB * HW_ * 64 * 2);

    upsample_k<<<(BB * 4 * HW_ + 255) / 256, 256, 0, stream>>>(bfp, biflow);

    wconv_k<<<(9 * 64 * 160 + 255) / 256, 256, 0, stream>>>(W1, WbL1, 64, 64, 145, 160);
    wconv_k<<<(9 * 64 * 64 + 255) / 256, 256, 0, stream>>>(W2, WbL2, 64, 64, 64, 64);
    wconv_k<<<(9 * 64 * 64 + 255) / 256, 256, 0, stream>>>(W3, WbL3, 64, 64, 64, 64);
    wconv_k<<<(9 * 32 * 64 + 255) / 256, 256, 0, stream>>>(W4, WbL4, 32, 32, 64, 64);
    wconv_k<<<(9 * 32 * 32 + 255) / 256, 256, 0, stream>>>(W5, WbL5, 32, 32, 32, 32);
    wconv_k<<<(9 * 16 * 32 + 255) / 256, 256, 0, stream>>>(W6, WbL6, 16, 16, 32, 32);
    wconv_k<<<(9 * 16 * 32 + 255) / 256, 256, 0, stream>>>(W7, WbL7, 2, 16, 16, 32);

    for (int g = 0; g < BB; g += NB) {
        const int nb = (BB - g < NB) ? (BB - g) : NB;
        const int npix = nb * HW_;
        const float* f0g  = f0 + (size_t)g * FC * HW_;
        const float* f1g  = f1 + (size_t)g * FC * HW_;
        const float* ftfg = ftf + (size_t)g * FC * HW_;
        const float* btfg = btf + (size_t)g * FC * HW_;
        const float* bflg = biflow + (size_t)g * 4 * HW_;
        float* outg = out + (size_t)g * 4 * HW_;

        zero4_k<<<2048, 256, 0, stream>>>((uint4*)acc0, (long)nb * 33 * HW_ / 4);
        zero4_k<<<2048, 256, 0, stream>>>((uint4*)acc1, (long)nb * 33 * HW_ / 4);
        splat_k<<<(npix + 255) / 256, 256, 0, stream>>>(f0g, bflg, 0, acc0, nb);
        splat_k<<<(npix + 255) / 256, 256, 0, stream>>>(f1g, bflg, 2, acc1, nb);
        norm_k<<<(npix + 255) / 256, 256, 0, stream>>>(acc0, nb);
        norm_k<<<(npix + 255) / 256, 256, 0, stream>>>(acc1, nb);
        corr_k<<<(npix + 255) / 256, 256, 0, stream>>>(acc0, acc1, concat, nb);

        dim3 cg(5, 192, nb);
        for (int pass = 0; pass < 2; ++pass) {
            const float* wp = pass ? acc1 : acc0;
            const float* tf = pass ? btfg : ftfg;
            int chB = pass ? 2 : 0;
            fill_k<<<(npix * 8 + 255) / 256, 256, 0, stream>>>(wp, tf, concat, nb);
            mconv_k<4, 5, false, false><<<cg, 256, 0, stream>>>(concat, 160, 160, WbL1, bufA, 64, nullptr, nullptr, 0);
            mconv_k<4, 2, false, false><<<cg, 256, 0, stream>>>(bufA, 64, 64, WbL2, bufB, 64, nullptr, nullptr, 0);
            mconv_k<4, 2, true,  false><<<cg, 256, 0, stream>>>(bufB, 64, 64, WbL3, bufA, 64, nullptr, nullptr, 0);
            mconv_k<2, 2, false, false><<<cg, 256, 0, stream>>>(bufA, 64, 64, WbL4, bufB, 32, nullptr, nullptr, 0);
            mconv_k<2, 1, false, false><<<cg, 256, 0, stream>>>(bufB, 32, 32, WbL5, bufA, 32, nullptr, nullptr, 0);
            mconv_k<1, 1, false, false><<<cg, 256, 0, stream>>>(bufA, 32, 32, WbL6, bufB, 16, nullptr, nullptr, 0);
            mconv_k<1, 1, true,  true ><<<cg, 256, 0, stream>>>(bufB, 16, 16, WbL7, nullptr, 0, bflg, outg, chB);
        }
    }
}